// Round 10
// baseline (422.307 us; speedup 1.0000x reference)
//
#include <hip/hip_runtime.h>
#include <hip/hip_bf16.h>
#include <stdint.h>

// Problem constants (fixed by the reference)
#define HD      4096            // K (hidden)
#define MROWS   8192            // B*S
#define NQ      4096
#define NKV     1024
#define NTOT    6144            // NQ + 2*NKV
#define RMS_EPS 1e-6f

typedef __attribute__((ext_vector_type(8))) short bf16x8;
typedef __attribute__((ext_vector_type(16))) float f32x16;

static __device__ __forceinline__ unsigned short f2bf(float f) {
  union { float f; unsigned u; } a; a.f = f;
  unsigned r = a.u + 0x7FFFu + ((a.u >> 16) & 1u);   // RNE
  return (unsigned short)(r >> 16);
}

// ------- Fused prep: rmsnorm (blocks 0..8191) + 3 transposes (8192..32767) ---
__global__ __launch_bounds__(256) void prep_kernel(
    const float* __restrict__ x, const float* __restrict__ gamma,
    const float* __restrict__ wq, const float* __restrict__ wk,
    const float* __restrict__ wv,
    unsigned short* __restrict__ xn, unsigned short* __restrict__ wt) {
  __shared__ float smem[32 * 33];
  const int bid = blockIdx.x;
  const int t = threadIdx.x;
  if (bid < MROWS) {
    // ---- RMSNorm row ----
    const float4* xr = (const float4*)(x + (size_t)bid * HD);
    const float4* g4 = (const float4*)gamma;
    float4 v[4];
    float ss = 0.f;
#pragma unroll
    for (int i = 0; i < 4; ++i) {
      v[i] = xr[t + i * 256];
      ss += v[i].x * v[i].x + v[i].y * v[i].y + v[i].z * v[i].z + v[i].w * v[i].w;
    }
#pragma unroll
    for (int o = 32; o > 0; o >>= 1) ss += __shfl_xor(ss, o, 64);
    if ((t & 63) == 0) smem[t >> 6] = ss;
    __syncthreads();
    const float tot = smem[0] + smem[1] + smem[2] + smem[3];
    const float rstd = rsqrtf(tot * (1.f / HD) + RMS_EPS);
    ushort4* xo = (ushort4*)(xn + (size_t)bid * HD);
#pragma unroll
    for (int i = 0; i < 4; ++i) {
      const float4 g = g4[t + i * 256];
      ushort4 o;
      o.x = f2bf(v[i].x * rstd * g.x);
      o.y = f2bf(v[i].y * rstd * g.y);
      o.z = f2bf(v[i].z * rstd * g.z);
      o.w = f2bf(v[i].w * rstd * g.w);
      xo[t + i * 256] = o;
    }
  } else {
    // ---- Transpose tile: W[K][Nw] f32 -> Wt[Nw][K] bf16 ----
    int b2 = bid - MROWS;
    const float* w; unsigned short* dst; int Nw, nb, kt;
    if (b2 < 16384)      { w = wq; dst = wt;                           Nw = NQ;  nb = b2 & 127; kt = b2 >> 7; }
    else if (b2 < 20480) { b2 -= 16384; w = wk; dst = wt + (size_t)NQ * HD;         Nw = NKV; nb = b2 & 31; kt = b2 >> 5; }
    else                 { b2 -= 20480; w = wv; dst = wt + (size_t)(NQ + NKV) * HD; Nw = NKV; nb = b2 & 31; kt = b2 >> 5; }
    const int r = t >> 3, c4 = t & 7;
    const float4 vin = *(const float4*)&w[(size_t)(kt * 32 + r) * Nw + nb * 32 + c4 * 4];
    smem[r * 33 + c4 * 4 + 0] = vin.x;
    smem[r * 33 + c4 * 4 + 1] = vin.y;
    smem[r * 33 + c4 * 4 + 2] = vin.z;
    smem[r * 33 + c4 * 4 + 3] = vin.w;
    __syncthreads();
    ushort4 o;
    o.x = f2bf(smem[(c4 * 4 + 0) * 33 + r]);
    o.y = f2bf(smem[(c4 * 4 + 1) * 33 + r]);
    o.z = f2bf(smem[(c4 * 4 + 2) * 33 + r]);
    o.w = f2bf(smem[(c4 * 4 + 3) * 33 + r]);
    *(ushort4*)&dst[(size_t)(nb * 32 + r) * HD + kt * 32 + c4 * 4] = o;
  }
}

// ---- 256x256 m201-style bf16 GEMM, 32x32x16, 8 phases/2 K-tiles, 2-barrier ---
// C[M,N] = A[M,K] * Bt[N,K]^T ; M=8192, N=6144, K=4096. BK=64, 512 thr.
//
// Quadrants per tile: p1(qm0,qn0) p2(qm0,qn1) p3(qm1,qn0) p4(qm1,qn1).
// A read once per 2 phases (p1,p3 / p5,p7); B read once per tile (p1,p2 /
// p5,p6) and HELD -> 24 ds_read_b128 per K-tile per wave, ALL base+immediate
// (16 loop-invariant base ptrs, swizzle folded in) -> ~zero loop VALU.
//
// Region lifecycle (write -> reads -> next write), all gap>=1 legal because
// the 2nd barrier of a phase guarantees that phase's reads retired:
//   buf0 A: reads p1,p3 | staged p5,p6 (tile 2t+2)
//   buf0 B: reads p1,p2 | staged p3,p4 (tile 2t+2)
//   buf1 A: reads p5,p7 | staged p1,p2 of SAME iter (tile 2t+1, JIT)
//   buf1 B: reads p5,p6 | staged p7,p8 (tile 2t+3)
// VM ledger (VM4 at p4 and p8 only; 2 loads/STG; steady queue=4):
//   VM4@p4: {p7',p8',p1,p2,p3,p4} -> retires p7',p8' (B1[2t+1]) and p1,p2
//           (A1[2t+1]) -- exactly what p5..p7 read. Leaves {p3,p4}.
//   VM4@p8: {p3,p4,p5,p6,p7,p8} -> retires p3..p6 (B0,A0 of tile 2t+2)
//           -- what next-iter p1..p3 read. Leaves {p7,p8}.
//   Prologue: 6 regions (t0 A,B + t1 B), VM4 retires t0. Tail clamps kc.

static __device__ __forceinline__ void gload_lds16(const unsigned short* g,
                                                   unsigned short* l) {
  __builtin_amdgcn_global_load_lds(
      (const __attribute__((address_space(1))) void*)g,
      (__attribute__((address_space(3))) void*)l, 16, 0, 0);
}

#define VM4 asm volatile("s_waitcnt vmcnt(4)" ::: "memory")
#define VM0 asm volatile("s_waitcnt vmcnt(0)" ::: "memory")
#define BAR __builtin_amdgcn_s_barrier()

// 8 A frags (2 mi x 4 ks) of quadrant QM from base array AK (immediates only)
#define RDA(AK, QM)                                                            \
  do {                                                                         \
    _Pragma("unroll") for (int mi = 0; mi < 2; ++mi)                           \
      _Pragma("unroll") for (int ks = 0; ks < 4; ++ks)                         \
        ar[mi][ks] = *(const bf16x8*)(AK[ks] + (QM) * 8192 + mi * 4096);       \
  } while (0)

// 4 B frags (4 ks) of n-block QN from base array BK
#define RDB(DST, BK, QN)                                                       \
  do {                                                                         \
    _Pragma("unroll") for (int ks = 0; ks < 4; ++ks)                           \
      DST[ks] = *(const bf16x8*)(BK[ks] + (QN) * 4096);                        \
  } while (0)

// 8 MFMA: quadrant (QM, QN) over K=64, A=ar, B=BR
#define MMA8(QM, QN, BR)                                                       \
  do {                                                                         \
    __builtin_amdgcn_s_setprio(1);                                             \
    _Pragma("unroll") for (int ks = 0; ks < 4; ++ks)                           \
      _Pragma("unroll") for (int mi = 0; mi < 2; ++mi)                         \
        acc[(QM) * 2 + mi][QN] = __builtin_amdgcn_mfma_f32_32x32x16_bf16(      \
            ar[mi][ks], BR[ks], acc[(QM) * 2 + mi][QN], 0, 0, 0);              \
    __builtin_amdgcn_s_setprio(0);                                             \
  } while (0)

__global__ __launch_bounds__(512, 2) void gemm_qkv_kernel(
    const unsigned short* __restrict__ A,    // [MROWS][HD] bf16 (xn)
    const unsigned short* __restrict__ Bt,   // [NTOT][HD] bf16 (w^T)
    float* __restrict__ out) {
  // [mat A/B][buf][half][128 rows x 64 k] bf16 = 128 KiB total
  __shared__ unsigned short lds[2][2][2][8192] __attribute__((aligned(16)));

  // XCD-rectangular swizzle: grid 32mt x 24nt = 768 blocks, XCD = bid&7.
  const int bid = blockIdx.x;
  const int xcd = bid & 7;
  const int idx = bid >> 3;                  // 0..95
  const int sr  = idx >> 5;                  // sub-round 0..2
  const int i32 = idx & 31;
  const int mt  = (xcd >> 1) * 8 + (i32 >> 2);
  const int nt  = (xcd & 1) * 12 + sr * 4 + (i32 & 3);
  const int m0 = mt * 256, n0 = nt * 256;

  const int tid = threadIdx.x;
  const int w = tid >> 6, lane = tid & 63;
  const int wr = w >> 2, wc = w & 3;         // wave rows: wr*128+mb*32; cols: wc*64+qn*32
  const int r32 = lane & 31, hi = lane >> 5;
  const int swx = (r32 >> 1) & 7;            // bank swizzle field

  // 16 loop-invariant ds_read base pointers (swizzle + row folded in once)
  const int rowoff = r32 * 128;
  const char* a0k[4]; const char* a1k[4];
  const char* b0k[4]; const char* b1k[4];
#pragma unroll
  for (int ks = 0; ks < 4; ++ks) {
    const int sl = (((ks * 2 + hi) ^ swx) << 4);
    a0k[ks] = (const char*)&lds[0][0][wr][0] + rowoff + sl;
    a1k[ks] = (const char*)&lds[0][1][wr][0] + rowoff + sl;
    b0k[ks] = (const char*)&lds[1][0][wc >> 1][0] + (wc & 1) * 8192 + rowoff + sl;
    b1k[ks] = (const char*)&lds[1][1][wc >> 1][0] + (wc & 1) * 8192 + rowoff + sl;
  }

  // staging: linear LDS dest, inverse-swizzled global source (rule #21)
  const int wslot = w * 512;                 // wave-uniform LDS element base
  const int r3 = tid >> 3;                   // region row 0..63 within pass
  const unsigned scol = (unsigned)(((tid & 7) ^ ((r3 >> 1) & 7)) << 3);
  const unsigned so0 = (unsigned)r3 * HD + scol;
  const unsigned so1 = so0 + 64u * HD;

  const unsigned short* const Ab0 = A + (size_t)m0 * HD;          // A half0 rows
  const unsigned short* const Ab1 = Ab0 + (size_t)128 * HD;       // A half1
  const unsigned short* const Bb0 = Bt + (size_t)n0 * HD;         // B half0
  const unsigned short* const Bb1 = Bb0 + (size_t)128 * HD;       // B half1

  auto STG = [&](const unsigned short* g, unsigned short* l) {
    gload_lds16(g + so0, l + wslot);
    gload_lds16(g + so1, l + 4096 + wslot);
  };

  f32x16 acc[4][2];
#pragma unroll
  for (int i = 0; i < 4; ++i)
#pragma unroll
    for (int j = 0; j < 2; ++j) acc[i][j] = (f32x16)(0.f);

  bf16x8 ar[2][4];                           // A quadrant (read per 2 phases)
  bf16x8 br0[4], br1[4];                     // B n-blocks (held per tile)

  // prologue: t0 B, t0 A, t1 B (6 regions, 12 loads); VM4 retires all of t0.
  STG(Bb0,      &lds[1][0][0][0]);
  STG(Bb1,      &lds[1][0][1][0]);
  STG(Ab0,      &lds[0][0][0][0]);
  STG(Ab1,      &lds[0][0][1][0]);
  STG(Bb0 + 64, &lds[1][1][0][0]);
  STG(Bb1 + 64, &lds[1][1][1][0]);
  VM4;                                       // t0 retired; t1 B in flight
  BAR;

  for (int t = 0; t < 32; ++t) {
    const int kcs = (2 * t + 1) * 64;                  // tile 2t+1 (JIT A1)
    const int t2 = 2 * t + 2, t3 = 2 * t + 3;
    const int kc0 = (t2 < 64 ? t2 : 63) * 64;          // tile 2t+2 -> buf0
    const int kc1 = (t3 < 64 ? t3 : 63) * 64;          // tile 2t+3 -> buf1 B
    // ---- tile 2t (buf0) ----
    RDA(a0k, 0); RDB(br0, b0k, 0); STG(Ab0 + kcs, &lds[0][1][0][0]);      // p1
    BAR; MMA8(0, 0, br0); BAR;
    RDB(br1, b0k, 1);              STG(Ab1 + kcs, &lds[0][1][1][0]);      // p2
    BAR; MMA8(0, 1, br1); BAR;
    RDA(a0k, 1);                   STG(Bb0 + kc0, &lds[1][0][0][0]);      // p3
    BAR; MMA8(1, 0, br0); BAR;
                                   STG(Bb1 + kc0, &lds[1][0][1][0]); VM4; // p4
    BAR; MMA8(1, 1, br1); BAR;
    // ---- tile 2t+1 (buf1) ----
    RDA(a1k, 0); RDB(br0, b1k, 0); STG(Ab0 + kc0, &lds[0][0][0][0]);      // p5
    BAR; MMA8(0, 0, br0); BAR;
    RDB(br1, b1k, 1);              STG(Ab1 + kc0, &lds[0][0][1][0]);      // p6
    BAR; MMA8(0, 1, br1); BAR;
    RDA(a1k, 1);                   STG(Bb0 + kc1, &lds[1][1][0][0]);      // p7
    BAR; MMA8(1, 0, br0); BAR;
                                   STG(Bb1 + kc1, &lds[1][1][1][0]); VM4; // p8
    BAR; MMA8(1, 1, br1); BAR;
  }
  VM0;                                       // drain trailing clamped stages

  // epilogue: route this block's 256 columns to q / k / v region
  size_t obase; int ldc, nc;
  if (n0 < NQ)            { obase = 0;                                        ldc = NQ;  nc = n0; }
  else if (n0 < NQ + NKV) { obase = (size_t)MROWS * NQ;                       ldc = NKV; nc = n0 - NQ; }
  else                    { obase = (size_t)MROWS * NQ + (size_t)MROWS * NKV; ldc = NKV; nc = n0 - NQ - NKV; }

  // C/D layout (verified m74/m101): col = lane&31, row = (reg&3)+8*(reg>>2)+4*hi
#pragma unroll
  for (int I = 0; I < 4; ++I) {
    const int rbase = m0 + wr * 128 + I * 32 + hi * 4;
#pragma unroll
    for (int J = 0; J < 2; ++J) {
      const int col = nc + wc * 64 + J * 32 + r32;
#pragma unroll
      for (int reg = 0; reg < 16; ++reg) {
        const int row = rbase + (reg & 3) + 8 * (reg >> 2);
        out[obase + (size_t)row * ldc + col] = acc[I][J][reg];
      }
    }
  }
}

extern "C" void kernel_launch(void* const* d_in, const int* in_sizes, int n_in,
                              void* d_out, int out_size, void* d_ws, size_t ws_size,
                              hipStream_t stream) {
  const float* x     = (const float*)d_in[0];
  const float* gamma = (const float*)d_in[1];
  const float* wq    = (const float*)d_in[2];
  const float* wk    = (const float*)d_in[3];
  const float* wv    = (const float*)d_in[4];
  float* out = (float*)d_out;

  // workspace layout: xn bf16 [8192][4096] then wt bf16 [6144][4096]
  unsigned short* xn = (unsigned short*)d_ws;
  unsigned short* wt = xn + (size_t)MROWS * HD;

  prep_kernel<<<32768, 256, 0, stream>>>(x, gamma, wq, wk, wv, xn, wt);
  gemm_qkv_kernel<<<(MROWS / 256) * (NTOT / 256), 512, 0, stream>>>(xn, wt, out);
}